// Round 5
// baseline (324.537 us; speedup 1.0000x reference)
//
#include <hip/hip_runtime.h>

#define HDIM 64
#define BH 64          // histogram/sort blocks (one slice each)
#define BINS 12500     // LDS bins per phase (50 KB static LDS)
#define NPHASE 4       // 4 * 12500 = 50000 = N

// ---------------- small helpers ----------------

__device__ __forceinline__ int lbound(const int* __restrict__ b, int n, int v) {
    int lo = 0, hi = n;
    while (lo < hi) { int m = (lo + hi) >> 1; if (b[m] < v) lo = m + 1; else hi = m; }
    return lo;
}

// ---------------- CSR build: blocked LDS counting sort (no global atomics) ----------------

// Per-block full histograms of col (cntP) and row (degP) via LDS atomics.
// Partial counts stored as u16 (per-block count <= slice = 12500).
__global__ __launch_bounds__(256) void k_histL(const int* __restrict__ row,
                                               const int* __restrict__ col,
                                               unsigned short* __restrict__ cntP,
                                               unsigned short* __restrict__ degP,
                                               int E, int N, int slice) {
    __shared__ int hbin[BINS];
    int blk = blockIdx.x;
    int e0 = blk * slice;
    int e1 = min(e0 + slice, E);
    // phases over col -> cntP
    for (int p = 0; p < NPHASE; ++p) {
        int lo = p * BINS;
        int span = min(BINS, N - lo);
        for (int i = threadIdx.x; i < span; i += 256) hbin[i] = 0;
        __syncthreads();
        for (int e = e0 + threadIdx.x; e < e1; e += 256) {
            int c = col[e] - lo;
            if ((unsigned)c < (unsigned)span) atomicAdd(&hbin[c], 1);   // LDS atomic
        }
        __syncthreads();
        for (int i = threadIdx.x; i < span; i += 256)
            cntP[(size_t)blk * N + lo + i] = (unsigned short)hbin[i];
        __syncthreads();
    }
    // phases over row -> degP
    for (int p = 0; p < NPHASE; ++p) {
        int lo = p * BINS;
        int span = min(BINS, N - lo);
        for (int i = threadIdx.x; i < span; i += 256) hbin[i] = 0;
        __syncthreads();
        for (int e = e0 + threadIdx.x; e < e1; e += 256) {
            int r = row[e] - lo;
            if ((unsigned)r < (unsigned)span) atomicAdd(&hbin[r], 1);
        }
        __syncthreads();
        for (int i = threadIdx.x; i < span; i += 256)
            degP[(size_t)blk * N + lo + i] = (unsigned short)hbin[i];
        __syncthreads();
    }
}

// Per bin: block-exclusive prefix over cntP (in place), total -> cnt;
// deg total -> dis (fused).
__global__ void k_prefA(unsigned short* __restrict__ cntP,
                        const unsigned short* __restrict__ degP,
                        int* __restrict__ cnt, float* __restrict__ dis, int N) {
    int i = blockIdx.x * blockDim.x + threadIdx.x;
    if (i >= N) return;
    int run = 0;
    #pragma unroll 8
    for (int b = 0; b < BH; ++b) {
        int v = cntP[(size_t)b * N + i];
        cntP[(size_t)b * N + i] = (unsigned short)run;
        run += v;
    }
    cnt[i] = run;
    int d = 0;
    #pragma unroll 8
    for (int b = 0; b < BH; ++b) d += degP[(size_t)b * N + i];
    dis[i] = d > 0 ? rsqrtf((float)d) : 0.0f;
}

// Exclusive scan of cnt, 2-level. Level 1: per-1024 block scan.
__global__ __launch_bounds__(1024) void k_scan1(const int* __restrict__ cnt,
                                                int* __restrict__ start,
                                                int* __restrict__ bsum, int n) {
    __shared__ int sh[1024];
    int i = blockIdx.x * 1024 + threadIdx.x;
    int v = (i < n) ? cnt[i] : 0;
    sh[threadIdx.x] = v;
    __syncthreads();
    for (int off = 1; off < 1024; off <<= 1) {
        int t = 0;
        if (threadIdx.x >= off) t = sh[threadIdx.x - off];
        __syncthreads();
        sh[threadIdx.x] += t;
        __syncthreads();
    }
    if (i < n) start[i] = sh[threadIdx.x] - v;   // exclusive within block
    if (threadIdx.x == 1023) bsum[blockIdx.x] = sh[1023];
}

// Level 2: one wave, shuffle exclusive scan over block sums (nb <= 64).
__global__ void k_scan2(int* __restrict__ bsum, int nb) {
    int lane = threadIdx.x;
    if (lane >= 64) return;
    int v = (lane < nb) ? bsum[lane] : 0;
    int incl = v;
    #pragma unroll
    for (int off = 1; off < 64; off <<= 1) {
        int u = __shfl_up(incl, off, 64);
        if (lane >= off) incl += u;
    }
    if (lane < nb) bsum[lane] = incl - v;
}

// Level 3: add block offsets.
__global__ void k_scan3(int* __restrict__ start, const int* __restrict__ bsum, int n) {
    int i = blockIdx.x * blockDim.x + threadIdx.x;
    if (i < n) start[i] += bsum[i >> 10];
}

// Scatter: LDS cursors seeded with start[c] + blockPrefix[c]; local fetch-add
// gives globally unique positions. er[pos] = row(e).
__global__ __launch_bounds__(256) void k_sortfill(const int* __restrict__ row,
                                                  const int* __restrict__ col,
                                                  const unsigned short* __restrict__ cntP,
                                                  const int* __restrict__ start,
                                                  int* __restrict__ er,
                                                  int E, int N, int slice) {
    __shared__ int cur[BINS];
    int blk = blockIdx.x;
    int e0 = blk * slice;
    int e1 = min(e0 + slice, E);
    for (int p = 0; p < NPHASE; ++p) {
        int lo = p * BINS;
        int span = min(BINS, N - lo);
        for (int i = threadIdx.x; i < span; i += 256)
            cur[i] = start[lo + i] + (int)cntP[(size_t)blk * N + lo + i];
        __syncthreads();
        for (int e = e0 + threadIdx.x; e < e1; e += 256) {
            int c = col[e] - lo;
            if ((unsigned)c < (unsigned)span) {
                int pos = atomicAdd(&cur[c], 1);          // LDS fetch-add
                er[pos] = row[e];
            }
        }
        __syncthreads();
    }
}

// ---------------- main pipeline ----------------

// Gather 1: Tx[i][:] = sum over in-edges of (-dis[r]*dis[i]) * x[r][:]
// One wave per node; 4 lane-quarters each handle every 4th edge with float4
// row loads, combined across quarters by shuffle at the end.
__global__ __launch_bounds__(256) void k_gather1(const int* __restrict__ er,
                                                 const int* __restrict__ start,
                                                 const int* __restrict__ cnt,
                                                 const float* __restrict__ dis,
                                                 const float* __restrict__ x,
                                                 float* __restrict__ Tx, int n) {
    int i = blockIdx.x * 4 + (threadIdx.x >> 6);
    if (i >= n) return;
    int lane = threadIdx.x & 63;
    int q = lane >> 4;
    int s4 = (lane & 15) * 4;
    int s = start[i], nd = cnt[i];
    float di = dis[i];
    float4 acc = make_float4(0.f, 0.f, 0.f, 0.f);
    int k = q;
    for (; k + 4 < nd; k += 8) {
        int r0 = er[s + k], r1 = er[s + k + 4];
        float w0 = -dis[r0] * di, w1 = -dis[r1] * di;
        float4 v0 = *reinterpret_cast<const float4*>(&x[(size_t)r0 * HDIM + s4]);
        float4 v1 = *reinterpret_cast<const float4*>(&x[(size_t)r1 * HDIM + s4]);
        acc.x = fmaf(w0, v0.x, acc.x); acc.y = fmaf(w0, v0.y, acc.y);
        acc.z = fmaf(w0, v0.z, acc.z); acc.w = fmaf(w0, v0.w, acc.w);
        acc.x = fmaf(w1, v1.x, acc.x); acc.y = fmaf(w1, v1.y, acc.y);
        acc.z = fmaf(w1, v1.z, acc.z); acc.w = fmaf(w1, v1.w, acc.w);
    }
    if (k < nd) {
        int r0 = er[s + k];
        float w0 = -dis[r0] * di;
        float4 v0 = *reinterpret_cast<const float4*>(&x[(size_t)r0 * HDIM + s4]);
        acc.x = fmaf(w0, v0.x, acc.x); acc.y = fmaf(w0, v0.y, acc.y);
        acc.z = fmaf(w0, v0.z, acc.z); acc.w = fmaf(w0, v0.w, acc.w);
    }
    #pragma unroll
    for (int off = 16; off <= 32; off <<= 1) {
        acc.x += __shfl_xor(acc.x, off, 64);
        acc.y += __shfl_xor(acc.y, off, 64);
        acc.z += __shfl_xor(acc.z, off, 64);
        acc.w += __shfl_xor(acc.w, off, 64);
    }
    if (q == 0) *reinterpret_cast<float4*>(&Tx[(size_t)i * HDIM + s4]) = acc;
}

// h = x@W1[0] + Tx1@W1[1] + b1, in-place over Tx1, grid-stride; per-block
// column sum/sumsq merged into stats at the end (fused BN stats pass).
__global__ __launch_bounds__(256) void k_gemm1(const float* __restrict__ x,
                                               float* __restrict__ TxH,
                                               const float* __restrict__ W1,
                                               const float* __restrict__ b1,
                                               float* __restrict__ stats, int n) {
    __shared__ float Ws[2 * HDIM * HDIM];       // 32 KB
    __shared__ float xs[4][HDIM];
    __shared__ float ts[4][HDIM];
    int tid = threadIdx.x;
    for (int idx = tid; idx < 2 * HDIM * HDIM; idx += 256) Ws[idx] = W1[idx];

    int rr = tid >> 6;
    int j  = tid & 63;
    float bj = b1[j];
    const float* w0 = Ws;
    const float* w1 = Ws + HDIM * HDIM;
    float sacc = 0.f, ssacc = 0.f;

    for (int base = blockIdx.x * 4; base < n; base += gridDim.x * 4) {
        int r = base + rr;
        __syncthreads();
        if (r < n) {
            xs[rr][j] = x[(size_t)r * HDIM + j];
            ts[rr][j] = TxH[(size_t)r * HDIM + j];
        }
        __syncthreads();
        if (r < n) {
            float acc = bj;
            #pragma unroll 8
            for (int k = 0; k < HDIM; ++k) {
                acc = fmaf(xs[rr][k], w0[k * HDIM + j], acc);
                acc = fmaf(ts[rr][k], w1[k * HDIM + j], acc);
            }
            TxH[(size_t)r * HDIM + j] = acc;
            sacc += acc;
            ssacc = fmaf(acc, acc, ssacc);
        }
    }
    __syncthreads();
    xs[rr][j] = sacc;
    ts[rr][j] = ssacc;
    __syncthreads();
    if (rr == 0) {
        float s  = xs[0][j] + xs[1][j] + xs[2][j] + xs[3][j];
        float ss = ts[0][j] + ts[1][j] + ts[2][j] + ts[3][j];
        atomicAdd(&stats[j], s);
        atomicAdd(&stats[64 + j], ss);
    }
}

// BN scale/shift, u0 = W2[0]@linW, u1 = W2[1]@linW, c0 = b2.linW + linb
__global__ void k_prep(const float* __restrict__ stats,
                       const float* __restrict__ gamma, const float* __restrict__ beta,
                       const float* __restrict__ W2, const float* __restrict__ b2,
                       const float* __restrict__ linW, const float* __restrict__ linb,
                       float* __restrict__ scale, float* __restrict__ shift,
                       float* __restrict__ u0, float* __restrict__ u1,
                       float* __restrict__ c0, int n) {
    int k = threadIdx.x;
    if (k >= HDIM) return;
    float inv_n = 1.0f / (float)n;
    float mu  = stats[k] * inv_n;
    float var = stats[64 + k] * inv_n - mu * mu;
    float rs  = rsqrtf(var + 1e-5f);
    float sc  = rs * gamma[k];
    scale[k] = sc;
    shift[k] = beta[k] - mu * sc;
    float a0 = 0.f, a1 = 0.f;
    #pragma unroll 8
    for (int j = 0; j < HDIM; ++j) {
        float lw = linW[j];
        a0 = fmaf(W2[k * HDIM + j], lw, a0);
        a1 = fmaf(W2[HDIM * HDIM + k * HDIM + j], lw, a1);
    }
    u0[k] = a0;
    u1[k] = a1;
    if (k == 0) {
        float c = linb[0];
        for (int j = 0; j < HDIM; ++j) c = fmaf(b2[j], linW[j], c);
        c0[0] = c;
    }
}

// Per node: BN + LeakyReLU, a[i]=y.u0, t[i]=y.u1 (wave shuffle reduce).
__global__ __launch_bounds__(256) void k_node(const float* __restrict__ h,
                                              const float* __restrict__ scale,
                                              const float* __restrict__ shift,
                                              const float* __restrict__ u0,
                                              const float* __restrict__ u1,
                                              float* __restrict__ a, float* __restrict__ t,
                                              int n) {
    int i = blockIdx.x * 4 + (threadIdx.x >> 6);
    if (i >= n) return;
    int j = threadIdx.x & 63;
    float v = fmaf(h[(size_t)i * HDIM + j], scale[j], shift[j]);
    v = v >= 0.f ? v : 0.01f * v;
    float p0 = v * u0[j];
    float p1 = v * u1[j];
    #pragma unroll
    for (int off = 32; off > 0; off >>= 1) {
        p0 += __shfl_xor(p0, off, 64);
        p1 += __shfl_xor(p1, off, 64);
    }
    if (j == 0) { a[i] = p0; t[i] = p1; }
}

// Gather 2 (scalar): s2[i] = a[i] + sum over in-edges of (-dis[r]*dis[i]) * t[r]
__global__ void k_gather2(const int* __restrict__ er, const int* __restrict__ start,
                          const int* __restrict__ cnt, const float* __restrict__ dis,
                          const float* __restrict__ t, const float* __restrict__ a,
                          float* __restrict__ s2, int n) {
    int i = blockIdx.x * blockDim.x + threadIdx.x;
    if (i >= n) return;
    int s = start[i], nd = cnt[i];
    float di = dis[i];
    float acc = a[i];
    int k = 0;
    for (; k + 1 < nd; k += 2) {
        int r0 = er[s + k], r1 = er[s + k + 1];
        float v0 = -dis[r0] * di * t[r0];
        float v1 = -dis[r1] * di * t[r1];
        acc += v0 + v1;
    }
    if (k < nd) {
        int r0 = er[s + k];
        acc = fmaf(-dis[r0] * di, t[r0], acc);
    }
    s2[i] = acc;
}

// Pool: one block per graph; batch is sorted -> binary search the range.
__global__ __launch_bounds__(256) void k_pool2(const float* __restrict__ s2,
                                               const int* __restrict__ batch,
                                               const float* __restrict__ c0,
                                               const float* __restrict__ linb,
                                               float* __restrict__ out, int n) {
    int g = blockIdx.x;
    int lo = lbound(batch, n, g);
    int hi = lbound(batch, n, g + 1);
    float s = 0.f;
    for (int i = lo + threadIdx.x; i < hi; i += 256) s += s2[i];
    __shared__ float red[256];
    red[threadIdx.x] = s;
    __syncthreads();
    for (int off = 128; off > 0; off >>= 1) {
        if (threadIdx.x < off) red[threadIdx.x] += red[threadIdx.x + off];
        __syncthreads();
    }
    if (threadIdx.x == 0) {
        int cntg = hi - lo;
        out[g] = cntg > 0 ? red[0] / (float)cntg + c0[0] : linb[0];
    }
}

// ---------------- launch ----------------

extern "C" void kernel_launch(void* const* d_in, const int* in_sizes, int n_in,
                              void* d_out, int out_size, void* d_ws, size_t ws_size,
                              hipStream_t stream) {
    const float* x     = (const float*)d_in[0];
    const int*   eidx  = (const int*)d_in[1];
    const int*   batch = (const int*)d_in[2];
    const float* W1    = (const float*)d_in[3];
    const float* b1    = (const float*)d_in[4];
    const float* W2    = (const float*)d_in[5];
    const float* b2    = (const float*)d_in[6];
    const float* gamma = (const float*)d_in[7];
    const float* beta  = (const float*)d_in[8];
    const float* linW  = (const float*)d_in[9];
    const float* linb  = (const float*)d_in[10];
    float* out = (float*)d_out;

    const int N = in_sizes[0] / HDIM;       // 50000
    const int E = in_sizes[1] / 2;          // 800000
    const int G = out_size;                 // 100
    const int NB = (N + 1023) / 1024;       // scan blocks (49 <= 64)
    const int slice = (E + BH - 1) / BH;    // 12500

    const int* row = eidx;
    const int* col = eidx + E;

    // ---- workspace layout ----
    // TxH region first; cntP/degP (u16, 2 * BH * N * 2B = 12.8 MB) overlay it:
    // both are dead before gather1 writes TxH.
    char* wsb = (char*)d_ws;
    float* TxH  = (float*)wsb;               wsb += (size_t)N * HDIM * 4;
    unsigned short* cntP = (unsigned short*)TxH;            // BH*N u16
    unsigned short* degP = cntP + (size_t)BH * N;           // BH*N u16
    int*   cnt   = (int*)wsb;                wsb += (size_t)N * 4;
    int*   start = (int*)wsb;                wsb += (size_t)N * 4;
    int*   bsum  = (int*)wsb;                wsb += (size_t)NB * 4 + 64;
    int*   er    = (int*)wsb;                wsb += (size_t)E * 4;
    float* dis   = (float*)wsb;              wsb += (size_t)N * 4;
    float* a     = (float*)wsb;              wsb += (size_t)N * 4;
    float* t     = (float*)wsb;              wsb += (size_t)N * 4;
    float* s2    = (float*)wsb;              wsb += (size_t)N * 4;
    float* stats = (float*)wsb;              wsb += 128 * 4;
    float* scale = (float*)wsb;              wsb += HDIM * 4;
    float* shift = (float*)wsb;              wsb += HDIM * 4;
    float* u0    = (float*)wsb;              wsb += HDIM * 4;
    float* u1    = (float*)wsb;              wsb += HDIM * 4;
    float* c0    = (float*)wsb;              wsb += 64;

    hipMemsetAsync(stats, 0, 128 * 4, stream);

    k_histL<<<BH, 256, 0, stream>>>(row, col, cntP, degP, E, N, slice);
    k_prefA<<<(N + 255) / 256, 256, 0, stream>>>(cntP, degP, cnt, dis, N);
    k_scan1<<<NB, 1024, 0, stream>>>(cnt, start, bsum, N);
    k_scan2<<<1, 64, 0, stream>>>(bsum, NB);
    k_scan3<<<(N + 255) / 256, 256, 0, stream>>>(start, bsum, N);
    k_sortfill<<<BH, 256, 0, stream>>>(row, col, cntP, start, er, E, N, slice);
    k_gather1<<<(N + 3) / 4, 256, 0, stream>>>(er, start, cnt, dis, x, TxH, N);
    k_gemm1<<<1024, 256, 0, stream>>>(x, TxH, W1, b1, stats, N);
    k_prep<<<1, 64, 0, stream>>>(stats, gamma, beta, W2, b2, linW, linb,
                                 scale, shift, u0, u1, c0, N);
    k_node<<<(N + 3) / 4, 256, 0, stream>>>(TxH, scale, shift, u0, u1, a, t, N);
    k_gather2<<<(N + 255) / 256, 256, 0, stream>>>(er, start, cnt, dis, t, a, s2, N);
    k_pool2<<<G, 256, 0, stream>>>(s2, batch, c0, linb, out, N);
}

// Round 6
// 209.284 us; speedup vs baseline: 1.5507x; 1.5507x over previous
//
#include <hip/hip_runtime.h>

#define HDIM 64
#define BH 64            // edge slices (partials: 2 * BH * N * 2B = 12.8 MB, overlaid on TxH)
#define HNODES 25600     // nodes per hist phase (12800 packed u32 bins = 51.2 KB LDS)
#define HBINS 12800
#define SBINS 12544      // cursor bins per sortfill phase (50.2 KB LDS); 4 * 12544 >= N

// ---------------- small helpers ----------------

__device__ __forceinline__ int lbound(const int* __restrict__ b, int n, int v) {
    int lo = 0, hi = n;
    while (lo < hi) { int m = (lo + hi) >> 1; if (b[m] < v) lo = m + 1; else hi = m; }
    return lo;
}

// ---------------- CSR build: blocked LDS counting sort, phase-parallel ----------------

// grid = (BH, 4): y&1 = node-range phase, y>>1 = {col->cntP, row->degP}.
// One pass over the slice per block; two u16 counters packed per u32 LDS bin.
__global__ __launch_bounds__(256) void k_histP(const int* __restrict__ row,
                                               const int* __restrict__ col,
                                               unsigned short* __restrict__ cntP,
                                               unsigned short* __restrict__ degP,
                                               int E, int N, int slice) {
    __shared__ unsigned hbin[HBINS];
    int blk   = blockIdx.x;
    int phase = blockIdx.y & 1;
    int isRow = blockIdx.y >> 1;
    const int* keys = isRow ? row : col;
    unsigned short* outP = isRow ? degP : cntP;
    int lo = phase * HNODES;
    int spanN = min(HNODES, N - lo);          // 25600 or 24400 (always even)
    int binsU = (spanN + 1) >> 1;
    for (int i = threadIdx.x; i < binsU; i += 256) hbin[i] = 0;
    __syncthreads();
    int e0 = blk * slice, e1 = min(e0 + slice, E);
    for (int e = e0 + threadIdx.x; e < e1; e += 256) {
        int c = keys[e] - lo;
        if ((unsigned)c < (unsigned)spanN)
            atomicAdd(&hbin[c >> 1], 1u << ((c & 1) << 4));   // LDS atomic, packed
    }
    __syncthreads();
    unsigned* outU = (unsigned*)(outP + (size_t)blk * N + lo);  // even offset -> aligned
    for (int i = threadIdx.x; i < binsU; i += 256) outU[i] = hbin[i];
}

// Per bin: block-exclusive prefix over cntP (in place), total -> cnt;
// deg total -> dis (fused).
__global__ void k_prefA(unsigned short* __restrict__ cntP,
                        const unsigned short* __restrict__ degP,
                        int* __restrict__ cnt, float* __restrict__ dis, int N) {
    int i = blockIdx.x * blockDim.x + threadIdx.x;
    if (i >= N) return;
    int run = 0;
    #pragma unroll 8
    for (int b = 0; b < BH; ++b) {
        int v = cntP[(size_t)b * N + i];
        cntP[(size_t)b * N + i] = (unsigned short)run;
        run += v;
    }
    cnt[i] = run;
    int d = 0;
    #pragma unroll 8
    for (int b = 0; b < BH; ++b) d += degP[(size_t)b * N + i];
    dis[i] = d > 0 ? rsqrtf((float)d) : 0.0f;
}

// Exclusive scan of cnt, 2-level. Level 1: per-1024 block scan.
__global__ __launch_bounds__(1024) void k_scan1(const int* __restrict__ cnt,
                                                int* __restrict__ start,
                                                int* __restrict__ bsum, int n) {
    __shared__ int sh[1024];
    int i = blockIdx.x * 1024 + threadIdx.x;
    int v = (i < n) ? cnt[i] : 0;
    sh[threadIdx.x] = v;
    __syncthreads();
    for (int off = 1; off < 1024; off <<= 1) {
        int t = 0;
        if (threadIdx.x >= off) t = sh[threadIdx.x - off];
        __syncthreads();
        sh[threadIdx.x] += t;
        __syncthreads();
    }
    if (i < n) start[i] = sh[threadIdx.x] - v;   // exclusive within block
    if (threadIdx.x == 1023) bsum[blockIdx.x] = sh[1023];
}

// Level 2: one wave, shuffle exclusive scan over block sums (nb <= 64).
__global__ void k_scan2(int* __restrict__ bsum, int nb) {
    int lane = threadIdx.x;
    if (lane >= 64) return;
    int v = (lane < nb) ? bsum[lane] : 0;
    int incl = v;
    #pragma unroll
    for (int off = 1; off < 64; off <<= 1) {
        int u = __shfl_up(incl, off, 64);
        if (lane >= off) incl += u;
    }
    if (lane < nb) bsum[lane] = incl - v;
}

// Level 3: add block offsets.
__global__ void k_scan3(int* __restrict__ start, const int* __restrict__ bsum, int n) {
    int i = blockIdx.x * blockDim.x + threadIdx.x;
    if (i < n) start[i] += bsum[i >> 10];
}

// grid = (BH, 4): y = cursor-range phase. LDS cursors seeded with
// start[c] + blockPrefix[c]; local fetch-add -> globally unique er positions.
__global__ __launch_bounds__(256) void k_sortfill(const int* __restrict__ row,
                                                  const int* __restrict__ col,
                                                  const unsigned short* __restrict__ cntP,
                                                  const int* __restrict__ start,
                                                  int* __restrict__ er,
                                                  int E, int N, int slice) {
    __shared__ int cur[SBINS];
    int blk = blockIdx.x;
    int lo = blockIdx.y * SBINS;
    int span = min(SBINS, N - lo);
    for (int i = threadIdx.x; i < span; i += 256)
        cur[i] = start[lo + i] + (int)cntP[(size_t)blk * N + lo + i];
    __syncthreads();
    int e0 = blk * slice, e1 = min(e0 + slice, E);
    for (int e = e0 + threadIdx.x; e < e1; e += 256) {
        int c = col[e] - lo;
        int rv = row[e];
        if ((unsigned)c < (unsigned)span) {
            int pos = atomicAdd(&cur[c], 1);          // LDS fetch-add
            er[pos] = rv;
        }
    }
}

// ---------------- main pipeline ----------------

// Gather 1: Tx[i][:] = sum over in-edges of (-dis[r]*dis[i]) * x[r][:]
// One wave per node; 4 lane-quarters each handle every 4th edge with float4
// row loads, combined across quarters by shuffle at the end.
__global__ __launch_bounds__(256) void k_gather1(const int* __restrict__ er,
                                                 const int* __restrict__ start,
                                                 const int* __restrict__ cnt,
                                                 const float* __restrict__ dis,
                                                 const float* __restrict__ x,
                                                 float* __restrict__ Tx, int n) {
    int i = blockIdx.x * 4 + (threadIdx.x >> 6);
    if (i >= n) return;
    int lane = threadIdx.x & 63;
    int q = lane >> 4;
    int s4 = (lane & 15) * 4;
    int s = start[i], nd = cnt[i];
    float di = dis[i];
    float4 acc = make_float4(0.f, 0.f, 0.f, 0.f);
    int k = q;
    for (; k + 4 < nd; k += 8) {
        int r0 = er[s + k], r1 = er[s + k + 4];
        float w0 = -dis[r0] * di, w1 = -dis[r1] * di;
        float4 v0 = *reinterpret_cast<const float4*>(&x[(size_t)r0 * HDIM + s4]);
        float4 v1 = *reinterpret_cast<const float4*>(&x[(size_t)r1 * HDIM + s4]);
        acc.x = fmaf(w0, v0.x, acc.x); acc.y = fmaf(w0, v0.y, acc.y);
        acc.z = fmaf(w0, v0.z, acc.z); acc.w = fmaf(w0, v0.w, acc.w);
        acc.x = fmaf(w1, v1.x, acc.x); acc.y = fmaf(w1, v1.y, acc.y);
        acc.z = fmaf(w1, v1.z, acc.z); acc.w = fmaf(w1, v1.w, acc.w);
    }
    if (k < nd) {
        int r0 = er[s + k];
        float w0 = -dis[r0] * di;
        float4 v0 = *reinterpret_cast<const float4*>(&x[(size_t)r0 * HDIM + s4]);
        acc.x = fmaf(w0, v0.x, acc.x); acc.y = fmaf(w0, v0.y, acc.y);
        acc.z = fmaf(w0, v0.z, acc.z); acc.w = fmaf(w0, v0.w, acc.w);
    }
    #pragma unroll
    for (int off = 16; off <= 32; off <<= 1) {
        acc.x += __shfl_xor(acc.x, off, 64);
        acc.y += __shfl_xor(acc.y, off, 64);
        acc.z += __shfl_xor(acc.z, off, 64);
        acc.w += __shfl_xor(acc.w, off, 64);
    }
    if (q == 0) *reinterpret_cast<float4*>(&Tx[(size_t)i * HDIM + s4]) = acc;
}

// h = x@W1[0] + Tx1@W1[1] + b1, in-place over Tx1, grid-stride; per-block
// column sum/sumsq merged into stats at the end (fused BN stats pass).
__global__ __launch_bounds__(256) void k_gemm1(const float* __restrict__ x,
                                               float* __restrict__ TxH,
                                               const float* __restrict__ W1,
                                               const float* __restrict__ b1,
                                               float* __restrict__ stats, int n) {
    __shared__ float Ws[2 * HDIM * HDIM];       // 32 KB
    __shared__ float xs[4][HDIM];
    __shared__ float ts[4][HDIM];
    int tid = threadIdx.x;
    for (int idx = tid; idx < 2 * HDIM * HDIM; idx += 256) Ws[idx] = W1[idx];

    int rr = tid >> 6;
    int j  = tid & 63;
    float bj = b1[j];
    const float* w0 = Ws;
    const float* w1 = Ws + HDIM * HDIM;
    float sacc = 0.f, ssacc = 0.f;

    for (int base = blockIdx.x * 4; base < n; base += gridDim.x * 4) {
        int r = base + rr;
        __syncthreads();
        if (r < n) {
            xs[rr][j] = x[(size_t)r * HDIM + j];
            ts[rr][j] = TxH[(size_t)r * HDIM + j];
        }
        __syncthreads();
        if (r < n) {
            float acc = bj;
            #pragma unroll 8
            for (int k = 0; k < HDIM; ++k) {
                acc = fmaf(xs[rr][k], w0[k * HDIM + j], acc);
                acc = fmaf(ts[rr][k], w1[k * HDIM + j], acc);
            }
            TxH[(size_t)r * HDIM + j] = acc;
            sacc += acc;
            ssacc = fmaf(acc, acc, ssacc);
        }
    }
    __syncthreads();
    xs[rr][j] = sacc;
    ts[rr][j] = ssacc;
    __syncthreads();
    if (rr == 0) {
        float s  = xs[0][j] + xs[1][j] + xs[2][j] + xs[3][j];
        float ss = ts[0][j] + ts[1][j] + ts[2][j] + ts[3][j];
        atomicAdd(&stats[j], s);
        atomicAdd(&stats[64 + j], ss);
    }
}

// BN scale/shift, u0 = W2[0]@linW, u1 = W2[1]@linW, c0 = b2.linW + linb
__global__ void k_prep(const float* __restrict__ stats,
                       const float* __restrict__ gamma, const float* __restrict__ beta,
                       const float* __restrict__ W2, const float* __restrict__ b2,
                       const float* __restrict__ linW, const float* __restrict__ linb,
                       float* __restrict__ scale, float* __restrict__ shift,
                       float* __restrict__ u0, float* __restrict__ u1,
                       float* __restrict__ c0, int n) {
    int k = threadIdx.x;
    if (k >= HDIM) return;
    float inv_n = 1.0f / (float)n;
    float mu  = stats[k] * inv_n;
    float var = stats[64 + k] * inv_n - mu * mu;
    float rs  = rsqrtf(var + 1e-5f);
    float sc  = rs * gamma[k];
    scale[k] = sc;
    shift[k] = beta[k] - mu * sc;
    float a0 = 0.f, a1 = 0.f;
    #pragma unroll 8
    for (int j = 0; j < HDIM; ++j) {
        float lw = linW[j];
        a0 = fmaf(W2[k * HDIM + j], lw, a0);
        a1 = fmaf(W2[HDIM * HDIM + k * HDIM + j], lw, a1);
    }
    u0[k] = a0;
    u1[k] = a1;
    if (k == 0) {
        float c = linb[0];
        for (int j = 0; j < HDIM; ++j) c = fmaf(b2[j], linW[j], c);
        c0[0] = c;
    }
}

// Per node: BN + LeakyReLU, a[i]=y.u0, t[i]=y.u1 (wave shuffle reduce).
__global__ __launch_bounds__(256) void k_node(const float* __restrict__ h,
                                              const float* __restrict__ scale,
                                              const float* __restrict__ shift,
                                              const float* __restrict__ u0,
                                              const float* __restrict__ u1,
                                              float* __restrict__ a, float* __restrict__ t,
                                              int n) {
    int i = blockIdx.x * 4 + (threadIdx.x >> 6);
    if (i >= n) return;
    int j = threadIdx.x & 63;
    float v = fmaf(h[(size_t)i * HDIM + j], scale[j], shift[j]);
    v = v >= 0.f ? v : 0.01f * v;
    float p0 = v * u0[j];
    float p1 = v * u1[j];
    #pragma unroll
    for (int off = 32; off > 0; off >>= 1) {
        p0 += __shfl_xor(p0, off, 64);
        p1 += __shfl_xor(p1, off, 64);
    }
    if (j == 0) { a[i] = p0; t[i] = p1; }
}

// Gather 2 (scalar): s2[i] = a[i] + sum over in-edges of (-dis[r]*dis[i]) * t[r]
__global__ void k_gather2(const int* __restrict__ er, const int* __restrict__ start,
                          const int* __restrict__ cnt, const float* __restrict__ dis,
                          const float* __restrict__ t, const float* __restrict__ a,
                          float* __restrict__ s2, int n) {
    int i = blockIdx.x * blockDim.x + threadIdx.x;
    if (i >= n) return;
    int s = start[i], nd = cnt[i];
    float di = dis[i];
    float acc = a[i];
    int k = 0;
    for (; k + 1 < nd; k += 2) {
        int r0 = er[s + k], r1 = er[s + k + 1];
        float v0 = -dis[r0] * di * t[r0];
        float v1 = -dis[r1] * di * t[r1];
        acc += v0 + v1;
    }
    if (k < nd) {
        int r0 = er[s + k];
        acc = fmaf(-dis[r0] * di, t[r0], acc);
    }
    s2[i] = acc;
}

// Pool: one block per graph; batch is sorted -> binary search the range.
__global__ __launch_bounds__(256) void k_pool2(const float* __restrict__ s2,
                                               const int* __restrict__ batch,
                                               const float* __restrict__ c0,
                                               const float* __restrict__ linb,
                                               float* __restrict__ out, int n) {
    int g = blockIdx.x;
    int lo = lbound(batch, n, g);
    int hi = lbound(batch, n, g + 1);
    float s = 0.f;
    for (int i = lo + threadIdx.x; i < hi; i += 256) s += s2[i];
    __shared__ float red[256];
    red[threadIdx.x] = s;
    __syncthreads();
    for (int off = 128; off > 0; off >>= 1) {
        if (threadIdx.x < off) red[threadIdx.x] += red[threadIdx.x + off];
        __syncthreads();
    }
    if (threadIdx.x == 0) {
        int cntg = hi - lo;
        out[g] = cntg > 0 ? red[0] / (float)cntg + c0[0] : linb[0];
    }
}

// ---------------- launch ----------------

extern "C" void kernel_launch(void* const* d_in, const int* in_sizes, int n_in,
                              void* d_out, int out_size, void* d_ws, size_t ws_size,
                              hipStream_t stream) {
    const float* x     = (const float*)d_in[0];
    const int*   eidx  = (const int*)d_in[1];
    const int*   batch = (const int*)d_in[2];
    const float* W1    = (const float*)d_in[3];
    const float* b1    = (const float*)d_in[4];
    const float* W2    = (const float*)d_in[5];
    const float* b2    = (const float*)d_in[6];
    const float* gamma = (const float*)d_in[7];
    const float* beta  = (const float*)d_in[8];
    const float* linW  = (const float*)d_in[9];
    const float* linb  = (const float*)d_in[10];
    float* out = (float*)d_out;

    const int N = in_sizes[0] / HDIM;       // 50000
    const int E = in_sizes[1] / 2;          // 800000
    const int G = out_size;                 // 100
    const int NB = (N + 1023) / 1024;       // scan blocks (49 <= 64)
    const int slice = (E + BH - 1) / BH;    // 12500

    const int* row = eidx;
    const int* col = eidx + E;

    // ---- workspace layout ----
    // cntP/degP (u16, 12.8 MB) overlay TxH: both dead before gather1 writes TxH.
    char* wsb = (char*)d_ws;
    float* TxH  = (float*)wsb;               wsb += (size_t)N * HDIM * 4;
    unsigned short* cntP = (unsigned short*)TxH;            // BH*N u16
    unsigned short* degP = cntP + (size_t)BH * N;           // BH*N u16
    int*   cnt   = (int*)wsb;                wsb += (size_t)N * 4;
    int*   start = (int*)wsb;                wsb += (size_t)N * 4;
    int*   bsum  = (int*)wsb;                wsb += (size_t)NB * 4 + 64;
    int*   er    = (int*)wsb;                wsb += (size_t)E * 4;
    float* dis   = (float*)wsb;              wsb += (size_t)N * 4;
    float* a     = (float*)wsb;              wsb += (size_t)N * 4;
    float* t     = (float*)wsb;              wsb += (size_t)N * 4;
    float* s2    = (float*)wsb;              wsb += (size_t)N * 4;
    float* stats = (float*)wsb;              wsb += 128 * 4;
    float* scale = (float*)wsb;              wsb += HDIM * 4;
    float* shift = (float*)wsb;              wsb += HDIM * 4;
    float* u0    = (float*)wsb;              wsb += HDIM * 4;
    float* u1    = (float*)wsb;              wsb += HDIM * 4;
    float* c0    = (float*)wsb;              wsb += 64;

    hipMemsetAsync(stats, 0, 128 * 4, stream);

    k_histP<<<dim3(BH, 4), 256, 0, stream>>>(row, col, cntP, degP, E, N, slice);
    k_prefA<<<(N + 255) / 256, 256, 0, stream>>>(cntP, degP, cnt, dis, N);
    k_scan1<<<NB, 1024, 0, stream>>>(cnt, start, bsum, N);
    k_scan2<<<1, 64, 0, stream>>>(bsum, NB);
    k_scan3<<<(N + 255) / 256, 256, 0, stream>>>(start, bsum, N);
    k_sortfill<<<dim3(BH, 4), 256, 0, stream>>>(row, col, cntP, start, er, E, N, slice);
    k_gather1<<<(N + 3) / 4, 256, 0, stream>>>(er, start, cnt, dis, x, TxH, N);
    k_gemm1<<<1024, 256, 0, stream>>>(x, TxH, W1, b1, stats, N);
    k_prep<<<1, 64, 0, stream>>>(stats, gamma, beta, W2, b2, linW, linb,
                                 scale, shift, u0, u1, c0, N);
    k_node<<<(N + 3) / 4, 256, 0, stream>>>(TxH, scale, shift, u0, u1, a, t, N);
    k_gather2<<<(N + 255) / 256, 256, 0, stream>>>(er, start, cnt, dis, t, a, s2, N);
    k_pool2<<<G, 256, 0, stream>>>(s2, batch, c0, linb, out, N);
}

// Round 7
// 190.725 us; speedup vs baseline: 1.7016x; 1.0973x over previous
//
#include <hip/hip_runtime.h>

#define HDIM 64
#define BH 64            // edge slices (partials: 2 * BH * N * 2B = 12.8 MB, overlaid on TxH)
#define HNODES 25600     // nodes per hist phase (12800 packed u32 bins = 51.2 KB LDS)
#define HBINS 12800
#define SBINS 12544      // cursor bins per sortfill phase (50.2 KB LDS); 4 * 12544 >= N
#define GR 32            // rows per gemm tile

// ---------------- small helpers ----------------

__device__ __forceinline__ int lbound(const int* __restrict__ b, int n, int v) {
    int lo = 0, hi = n;
    while (lo < hi) { int m = (lo + hi) >> 1; if (b[m] < v) lo = m + 1; else hi = m; }
    return lo;
}

// ---------------- CSR build: blocked LDS counting sort, phase-parallel ----------------

// grid = (BH, 4): y&1 = node-range phase, y>>1 = {col->cntP, row->degP}.
// One pass over the slice per block; two u16 counters packed per u32 LDS bin.
__global__ __launch_bounds__(256) void k_histP(const int* __restrict__ row,
                                               const int* __restrict__ col,
                                               unsigned short* __restrict__ cntP,
                                               unsigned short* __restrict__ degP,
                                               int E, int N, int slice) {
    __shared__ unsigned hbin[HBINS];
    int blk   = blockIdx.x;
    int phase = blockIdx.y & 1;
    int isRow = blockIdx.y >> 1;
    const int* keys = isRow ? row : col;
    unsigned short* outP = isRow ? degP : cntP;
    int lo = phase * HNODES;
    int spanN = min(HNODES, N - lo);          // 25600 or 24400 (always even)
    int binsU = (spanN + 1) >> 1;
    for (int i = threadIdx.x; i < binsU; i += 256) hbin[i] = 0;
    __syncthreads();
    int e0 = blk * slice, e1 = min(e0 + slice, E);
    for (int e = e0 + threadIdx.x; e < e1; e += 256) {
        int c = keys[e] - lo;
        if ((unsigned)c < (unsigned)spanN)
            atomicAdd(&hbin[c >> 1], 1u << ((c & 1) << 4));   // LDS atomic, packed
    }
    __syncthreads();
    unsigned* outU = (unsigned*)(outP + (size_t)blk * N + lo);  // even offset -> aligned
    for (int i = threadIdx.x; i < binsU; i += 256) outU[i] = hbin[i];
}

// Per bin: block-exclusive prefix over cntP (in place), total -> cnt;
// deg total -> dis (fused).
__global__ void k_prefA(unsigned short* __restrict__ cntP,
                        const unsigned short* __restrict__ degP,
                        int* __restrict__ cnt, float* __restrict__ dis, int N) {
    int i = blockIdx.x * blockDim.x + threadIdx.x;
    if (i >= N) return;
    int run = 0;
    #pragma unroll 8
    for (int b = 0; b < BH; ++b) {
        int v = cntP[(size_t)b * N + i];
        cntP[(size_t)b * N + i] = (unsigned short)run;
        run += v;
    }
    cnt[i] = run;
    int d = 0;
    #pragma unroll 8
    for (int b = 0; b < BH; ++b) d += degP[(size_t)b * N + i];
    dis[i] = d > 0 ? rsqrtf((float)d) : 0.0f;
}

// Exclusive scan of cnt, 2-level. Level 1: shuffle-based per-1024 block scan.
__global__ __launch_bounds__(1024) void k_scan1(const int* __restrict__ cnt,
                                                int* __restrict__ start,
                                                int* __restrict__ bsum, int n) {
    __shared__ int wsum[16];
    int i = blockIdx.x * 1024 + threadIdx.x;
    int lane = threadIdx.x & 63, w = threadIdx.x >> 6;
    int v = (i < n) ? cnt[i] : 0;
    int incl = v;
    #pragma unroll
    for (int off = 1; off < 64; off <<= 1) {
        int u = __shfl_up(incl, off, 64);
        if (lane >= off) incl += u;
    }
    if (lane == 63) wsum[w] = incl;
    __syncthreads();
    if (w == 0) {
        int s = (lane < 16) ? wsum[lane] : 0;
        int si = s;
        #pragma unroll
        for (int off = 1; off < 16; off <<= 1) {
            int u = __shfl_up(si, off, 64);
            if (lane >= off) si += u;
        }
        if (lane < 16) wsum[lane] = si - s;   // exclusive wave offsets
    }
    __syncthreads();
    int excl = incl - v + wsum[w];
    if (i < n) start[i] = excl;
    if (threadIdx.x == 1023) bsum[blockIdx.x] = excl + v;
}

// Level 2: one wave, shuffle exclusive scan over block sums (nb <= 64).
__global__ void k_scan2(int* __restrict__ bsum, int nb) {
    int lane = threadIdx.x;
    if (lane >= 64) return;
    int v = (lane < nb) ? bsum[lane] : 0;
    int incl = v;
    #pragma unroll
    for (int off = 1; off < 64; off <<= 1) {
        int u = __shfl_up(incl, off, 64);
        if (lane >= off) incl += u;
    }
    if (lane < nb) bsum[lane] = incl - v;
}

// Level 3: add block offsets.
__global__ void k_scan3(int* __restrict__ start, const int* __restrict__ bsum, int n) {
    int i = blockIdx.x * blockDim.x + threadIdx.x;
    if (i < n) start[i] += bsum[i >> 10];
}

// grid = (BH, 4): y = cursor-range phase. LDS cursors seeded with
// start[c] + blockPrefix[c]; local fetch-add -> globally unique er positions.
__global__ __launch_bounds__(256) void k_sortfill(const int* __restrict__ row,
                                                  const int* __restrict__ col,
                                                  const unsigned short* __restrict__ cntP,
                                                  const int* __restrict__ start,
                                                  int* __restrict__ er,
                                                  int E, int N, int slice) {
    __shared__ int cur[SBINS];
    int blk = blockIdx.x;
    int lo = blockIdx.y * SBINS;
    int span = min(SBINS, N - lo);
    for (int i = threadIdx.x; i < span; i += 256)
        cur[i] = start[lo + i] + (int)cntP[(size_t)blk * N + lo + i];
    __syncthreads();
    int e0 = blk * slice, e1 = min(e0 + slice, E);
    for (int e = e0 + threadIdx.x; e < e1; e += 256) {
        int c = col[e] - lo;
        int rv = row[e];
        if ((unsigned)c < (unsigned)span) {
            int pos = atomicAdd(&cur[c], 1);          // LDS fetch-add
            er[pos] = rv;
        }
    }
}

// ---------------- main pipeline ----------------

// Gather 1: Tx[i][:] = sum over in-edges of (-dis[r]*dis[i]) * x[r][:]
// One wave per node; 4 lane-quarters each handle every 4th edge with float4
// row loads, combined across quarters by shuffle at the end.
__global__ __launch_bounds__(256) void k_gather1(const int* __restrict__ er,
                                                 const int* __restrict__ start,
                                                 const int* __restrict__ cnt,
                                                 const float* __restrict__ dis,
                                                 const float* __restrict__ x,
                                                 float* __restrict__ Tx, int n) {
    int i = blockIdx.x * 4 + (threadIdx.x >> 6);
    if (i >= n) return;
    int lane = threadIdx.x & 63;
    int q = lane >> 4;
    int s4 = (lane & 15) * 4;
    int s = start[i], nd = cnt[i];
    float di = dis[i];
    float4 acc = make_float4(0.f, 0.f, 0.f, 0.f);
    int k = q;
    for (; k + 4 < nd; k += 8) {
        int r0 = er[s + k], r1 = er[s + k + 4];
        float w0 = -dis[r0] * di, w1 = -dis[r1] * di;
        float4 v0 = *reinterpret_cast<const float4*>(&x[(size_t)r0 * HDIM + s4]);
        float4 v1 = *reinterpret_cast<const float4*>(&x[(size_t)r1 * HDIM + s4]);
        acc.x = fmaf(w0, v0.x, acc.x); acc.y = fmaf(w0, v0.y, acc.y);
        acc.z = fmaf(w0, v0.z, acc.z); acc.w = fmaf(w0, v0.w, acc.w);
        acc.x = fmaf(w1, v1.x, acc.x); acc.y = fmaf(w1, v1.y, acc.y);
        acc.z = fmaf(w1, v1.z, acc.z); acc.w = fmaf(w1, v1.w, acc.w);
    }
    if (k < nd) {
        int r0 = er[s + k];
        float w0 = -dis[r0] * di;
        float4 v0 = *reinterpret_cast<const float4*>(&x[(size_t)r0 * HDIM + s4]);
        acc.x = fmaf(w0, v0.x, acc.x); acc.y = fmaf(w0, v0.y, acc.y);
        acc.z = fmaf(w0, v0.z, acc.z); acc.w = fmaf(w0, v0.w, acc.w);
    }
    #pragma unroll
    for (int off = 16; off <= 32; off <<= 1) {
        acc.x += __shfl_xor(acc.x, off, 64);
        acc.y += __shfl_xor(acc.y, off, 64);
        acc.z += __shfl_xor(acc.z, off, 64);
        acc.w += __shfl_xor(acc.w, off, 64);
    }
    if (q == 0) *reinterpret_cast<float4*>(&Tx[(size_t)i * HDIM + s4]) = acc;
}

// h = x@W1[0] + Tx1@W1[1] + b1, in-place over Tx1. Register-blocked: each
// thread holds BOTH W columns for its j in 128 VGPRs (statically indexed);
// 32-row tiles of x/TxH staged in LDS, read back as wave-uniform b128
// broadcasts (conflict-free). 4 FMA per LDS instr vs 0.5 before.
// Per-block column sum/sumsq merged into stats at the end.
__global__ __launch_bounds__(256) void k_gemm1(const float* __restrict__ x,
                                               float* __restrict__ TxH,
                                               const float* __restrict__ W1,
                                               const float* __restrict__ b1,
                                               float* __restrict__ stats, int n) {
    __shared__ float xs[GR][HDIM];      // 8 KB
    __shared__ float ts[GR][HDIM];      // 8 KB
    int tid = threadIdx.x;
    int j = tid & 63, w = tid >> 6;

    float4 w0r[16], w1r[16];
    #pragma unroll
    for (int k4 = 0; k4 < 16; ++k4) {
        w0r[k4].x = W1[(k4 * 4 + 0) * HDIM + j];
        w0r[k4].y = W1[(k4 * 4 + 1) * HDIM + j];
        w0r[k4].z = W1[(k4 * 4 + 2) * HDIM + j];
        w0r[k4].w = W1[(k4 * 4 + 3) * HDIM + j];
        w1r[k4].x = W1[4096 + (k4 * 4 + 0) * HDIM + j];
        w1r[k4].y = W1[4096 + (k4 * 4 + 1) * HDIM + j];
        w1r[k4].z = W1[4096 + (k4 * 4 + 2) * HDIM + j];
        w1r[k4].w = W1[4096 + (k4 * 4 + 3) * HDIM + j];
    }
    float bj = b1[j];
    float sacc = 0.f, ssacc = 0.f;

    for (int base = blockIdx.x * GR; base < n; base += gridDim.x * GR) {
        __syncthreads();                 // protect previous iteration's LDS reads
        for (int v = tid; v < GR * HDIM / 4; v += 256) {
            int r = base + (v >> 4);     // 16 float4 per row
            if (r < n) {
                int c = (v & 15) * 4;
                ((float4*)xs)[v] = *(const float4*)&x[(size_t)r * HDIM + c];
                ((float4*)ts)[v] = *(const float4*)&TxH[(size_t)r * HDIM + c];
            }
        }
        __syncthreads();
        #pragma unroll
        for (int m = 0; m < 8; ++m) {
            int lr = w * 8 + m;
            int r = base + lr;
            if (r < n) {
                const float4* xr = (const float4*)xs[lr];
                const float4* tr = (const float4*)ts[lr];
                float acc = bj;
                #pragma unroll
                for (int k4 = 0; k4 < 16; ++k4) {
                    float4 xv = xr[k4], tv = tr[k4];
                    acc = fmaf(xv.x, w0r[k4].x, acc);
                    acc = fmaf(xv.y, w0r[k4].y, acc);
                    acc = fmaf(xv.z, w0r[k4].z, acc);
                    acc = fmaf(xv.w, w0r[k4].w, acc);
                    acc = fmaf(tv.x, w1r[k4].x, acc);
                    acc = fmaf(tv.y, w1r[k4].y, acc);
                    acc = fmaf(tv.z, w1r[k4].z, acc);
                    acc = fmaf(tv.w, w1r[k4].w, acc);
                }
                TxH[(size_t)r * HDIM + j] = acc;
                sacc += acc;
                ssacc = fmaf(acc, acc, ssacc);
            }
        }
    }
    __syncthreads();
    xs[w][j] = sacc;
    ts[w][j] = ssacc;
    __syncthreads();
    if (w == 0) {
        float s  = xs[0][j] + xs[1][j] + xs[2][j] + xs[3][j];
        float ss = ts[0][j] + ts[1][j] + ts[2][j] + ts[3][j];
        atomicAdd(&stats[j], s);
        atomicAdd(&stats[64 + j], ss);
    }
}

// BN scale/shift, u0 = W2[0]@linW, u1 = W2[1]@linW, c0 = b2.linW + linb
__global__ void k_prep(const float* __restrict__ stats,
                       const float* __restrict__ gamma, const float* __restrict__ beta,
                       const float* __restrict__ W2, const float* __restrict__ b2,
                       const float* __restrict__ linW, const float* __restrict__ linb,
                       float* __restrict__ scale, float* __restrict__ shift,
                       float* __restrict__ u0, float* __restrict__ u1,
                       float* __restrict__ c0, int n) {
    int k = threadIdx.x;
    if (k >= HDIM) return;
    float inv_n = 1.0f / (float)n;
    float mu  = stats[k] * inv_n;
    float var = stats[64 + k] * inv_n - mu * mu;
    float rs  = rsqrtf(var + 1e-5f);
    float sc  = rs * gamma[k];
    scale[k] = sc;
    shift[k] = beta[k] - mu * sc;
    float a0 = 0.f, a1 = 0.f;
    #pragma unroll 8
    for (int j = 0; j < HDIM; ++j) {
        float lw = linW[j];
        a0 = fmaf(W2[k * HDIM + j], lw, a0);
        a1 = fmaf(W2[HDIM * HDIM + k * HDIM + j], lw, a1);
    }
    u0[k] = a0;
    u1[k] = a1;
    if (k == 0) {
        float c = linb[0];
        for (int j = 0; j < HDIM; ++j) c = fmaf(b2[j], linW[j], c);
        c0[0] = c;
    }
}

// Per node: BN + LeakyReLU, a[i]=y.u0, t[i]=y.u1 (wave shuffle reduce).
__global__ __launch_bounds__(256) void k_node(const float* __restrict__ h,
                                              const float* __restrict__ scale,
                                              const float* __restrict__ shift,
                                              const float* __restrict__ u0,
                                              const float* __restrict__ u1,
                                              float* __restrict__ a, float* __restrict__ t,
                                              int n) {
    int i = blockIdx.x * 4 + (threadIdx.x >> 6);
    if (i >= n) return;
    int j = threadIdx.x & 63;
    float v = fmaf(h[(size_t)i * HDIM + j], scale[j], shift[j]);
    v = v >= 0.f ? v : 0.01f * v;
    float p0 = v * u0[j];
    float p1 = v * u1[j];
    #pragma unroll
    for (int off = 32; off > 0; off >>= 1) {
        p0 += __shfl_xor(p0, off, 64);
        p1 += __shfl_xor(p1, off, 64);
    }
    if (j == 0) { a[i] = p0; t[i] = p1; }
}

// Gather 2 (scalar): s2[i] = a[i] + sum over in-edges of (-dis[r]*dis[i]) * t[r]
__global__ void k_gather2(const int* __restrict__ er, const int* __restrict__ start,
                          const int* __restrict__ cnt, const float* __restrict__ dis,
                          const float* __restrict__ t, const float* __restrict__ a,
                          float* __restrict__ s2, int n) {
    int i = blockIdx.x * blockDim.x + threadIdx.x;
    if (i >= n) return;
    int s = start[i], nd = cnt[i];
    float di = dis[i];
    float acc = a[i];
    int k = 0;
    for (; k + 1 < nd; k += 2) {
        int r0 = er[s + k], r1 = er[s + k + 1];
        float v0 = -dis[r0] * di * t[r0];
        float v1 = -dis[r1] * di * t[r1];
        acc += v0 + v1;
    }
    if (k < nd) {
        int r0 = er[s + k];
        acc = fmaf(-dis[r0] * di, t[r0], acc);
    }
    s2[i] = acc;
}

// Pool: one block per graph; batch is sorted -> binary search the range.
__global__ __launch_bounds__(256) void k_pool2(const float* __restrict__ s2,
                                               const int* __restrict__ batch,
                                               const float* __restrict__ c0,
                                               const float* __restrict__ linb,
                                               float* __restrict__ out, int n) {
    int g = blockIdx.x;
    int lo = lbound(batch, n, g);
    int hi = lbound(batch, n, g + 1);
    float s = 0.f;
    for (int i = lo + threadIdx.x; i < hi; i += 256) s += s2[i];
    __shared__ float red[256];
    red[threadIdx.x] = s;
    __syncthreads();
    for (int off = 128; off > 0; off >>= 1) {
        if (threadIdx.x < off) red[threadIdx.x] += red[threadIdx.x + off];
        __syncthreads();
    }
    if (threadIdx.x == 0) {
        int cntg = hi - lo;
        out[g] = cntg > 0 ? red[0] / (float)cntg + c0[0] : linb[0];
    }
}

// ---------------- launch ----------------

extern "C" void kernel_launch(void* const* d_in, const int* in_sizes, int n_in,
                              void* d_out, int out_size, void* d_ws, size_t ws_size,
                              hipStream_t stream) {
    const float* x     = (const float*)d_in[0];
    const int*   eidx  = (const int*)d_in[1];
    const int*   batch = (const int*)d_in[2];
    const float* W1    = (const float*)d_in[3];
    const float* b1    = (const float*)d_in[4];
    const float* W2    = (const float*)d_in[5];
    const float* b2    = (const float*)d_in[6];
    const float* gamma = (const float*)d_in[7];
    const float* beta  = (const float*)d_in[8];
    const float* linW  = (const float*)d_in[9];
    const float* linb  = (const float*)d_in[10];
    float* out = (float*)d_out;

    const int N = in_sizes[0] / HDIM;       // 50000
    const int E = in_sizes[1] / 2;          // 800000
    const int G = out_size;                 // 100
    const int NB = (N + 1023) / 1024;       // scan blocks (49 <= 64)
    const int slice = (E + BH - 1) / BH;    // 12500

    const int* row = eidx;
    const int* col = eidx + E;

    // ---- workspace layout ----
    // cntP/degP (u16, 12.8 MB) overlay TxH: both dead before gather1 writes TxH.
    char* wsb = (char*)d_ws;
    float* TxH  = (float*)wsb;               wsb += (size_t)N * HDIM * 4;
    unsigned short* cntP = (unsigned short*)TxH;            // BH*N u16
    unsigned short* degP = cntP + (size_t)BH * N;           // BH*N u16
    int*   cnt   = (int*)wsb;                wsb += (size_t)N * 4;
    int*   start = (int*)wsb;                wsb += (size_t)N * 4;
    int*   bsum  = (int*)wsb;                wsb += (size_t)NB * 4 + 64;
    int*   er    = (int*)wsb;                wsb += (size_t)E * 4;
    float* dis   = (float*)wsb;              wsb += (size_t)N * 4;
    float* a     = (float*)wsb;              wsb += (size_t)N * 4;
    float* t     = (float*)wsb;              wsb += (size_t)N * 4;
    float* s2    = (float*)wsb;              wsb += (size_t)N * 4;
    float* stats = (float*)wsb;              wsb += 128 * 4;
    float* scale = (float*)wsb;              wsb += HDIM * 4;
    float* shift = (float*)wsb;              wsb += HDIM * 4;
    float* u0    = (float*)wsb;              wsb += HDIM * 4;
    float* u1    = (float*)wsb;              wsb += HDIM * 4;
    float* c0    = (float*)wsb;              wsb += 64;

    hipMemsetAsync(stats, 0, 128 * 4, stream);

    k_histP<<<dim3(BH, 4), 256, 0, stream>>>(row, col, cntP, degP, E, N, slice);
    k_prefA<<<(N + 255) / 256, 256, 0, stream>>>(cntP, degP, cnt, dis, N);
    k_scan1<<<NB, 1024, 0, stream>>>(cnt, start, bsum, N);
    k_scan2<<<1, 64, 0, stream>>>(bsum, NB);
    k_scan3<<<(N + 255) / 256, 256, 0, stream>>>(start, bsum, N);
    k_sortfill<<<dim3(BH, 4), 256, 0, stream>>>(row, col, cntP, start, er, E, N, slice);
    k_gather1<<<(N + 3) / 4, 256, 0, stream>>>(er, start, cnt, dis, x, TxH, N);
    k_gemm1<<<512, 256, 0, stream>>>(x, TxH, W1, b1, stats, N);
    k_prep<<<1, 64, 0, stream>>>(stats, gamma, beta, W2, b2, linW, linb,
                                 scale, shift, u0, u1, c0, N);
    k_node<<<(N + 3) / 4, 256, 0, stream>>>(TxH, scale, shift, u0, u1, a, t, N);
    k_gather2<<<(N + 255) / 256, 256, 0, stream>>>(er, start, cnt, dis, t, a, s2, N);
    k_pool2<<<G, 256, 0, stream>>>(s2, batch, c0, linb, out, N);
}

// Round 8
// 168.965 us; speedup vs baseline: 1.9207x; 1.1288x over previous
//
#include <hip/hip_runtime.h>

#define HDIM 64
#define BH 64            // edge slices (partials: 2 * BH * N * 2B = 12.8 MB, overlaid on TxH)
#define HNODES 25600     // nodes per hist phase (12800 packed u32 bins = 51.2 KB LDS)
#define HBINS 12800
#define SBINS 12544      // cursor bins per sortfill phase (50.2 KB LDS); 4 * 12544 >= N
#define GR 32            // rows per gemm tile

// ---------------- small helpers ----------------

__device__ __forceinline__ int lbound(const int* __restrict__ b, int n, int v) {
    int lo = 0, hi = n;
    while (lo < hi) { int m = (lo + hi) >> 1; if (b[m] < v) lo = m + 1; else hi = m; }
    return lo;
}

// ---------------- CSR build: blocked LDS counting sort, phase-parallel ----------------

__global__ __launch_bounds__(256) void k_histP(const int* __restrict__ row,
                                               const int* __restrict__ col,
                                               unsigned short* __restrict__ cntP,
                                               unsigned short* __restrict__ degP,
                                               int E, int N, int slice) {
    __shared__ unsigned hbin[HBINS];
    int blk   = blockIdx.x;
    int phase = blockIdx.y & 1;
    int isRow = blockIdx.y >> 1;
    const int* keys = isRow ? row : col;
    unsigned short* outP = isRow ? degP : cntP;
    int lo = phase * HNODES;
    int spanN = min(HNODES, N - lo);
    int binsU = (spanN + 1) >> 1;
    for (int i = threadIdx.x; i < binsU; i += 256) hbin[i] = 0;
    __syncthreads();
    int e0 = blk * slice, e1 = min(e0 + slice, E);
    for (int e = e0 + threadIdx.x; e < e1; e += 256) {
        int c = keys[e] - lo;
        if ((unsigned)c < (unsigned)spanN)
            atomicAdd(&hbin[c >> 1], 1u << ((c & 1) << 4));   // LDS atomic, packed
    }
    __syncthreads();
    unsigned* outU = (unsigned*)(outP + (size_t)blk * N + lo);
    for (int i = threadIdx.x; i < binsU; i += 256) outU[i] = hbin[i];
}

__global__ void k_prefA(unsigned short* __restrict__ cntP,
                        const unsigned short* __restrict__ degP,
                        int* __restrict__ cnt, float* __restrict__ dis, int N) {
    int i = blockIdx.x * blockDim.x + threadIdx.x;
    if (i >= N) return;
    int run = 0;
    #pragma unroll 8
    for (int b = 0; b < BH; ++b) {
        int v = cntP[(size_t)b * N + i];
        cntP[(size_t)b * N + i] = (unsigned short)run;
        run += v;
    }
    cnt[i] = run;
    int d = 0;
    #pragma unroll 8
    for (int b = 0; b < BH; ++b) d += degP[(size_t)b * N + i];
    dis[i] = d > 0 ? rsqrtf((float)d) : 0.0f;
}

__global__ __launch_bounds__(1024) void k_scan1(const int* __restrict__ cnt,
                                                int* __restrict__ start,
                                                int* __restrict__ bsum, int n) {
    __shared__ int wsum[16];
    int i = blockIdx.x * 1024 + threadIdx.x;
    int lane = threadIdx.x & 63, w = threadIdx.x >> 6;
    int v = (i < n) ? cnt[i] : 0;
    int incl = v;
    #pragma unroll
    for (int off = 1; off < 64; off <<= 1) {
        int u = __shfl_up(incl, off, 64);
        if (lane >= off) incl += u;
    }
    if (lane == 63) wsum[w] = incl;
    __syncthreads();
    if (w == 0) {
        int s = (lane < 16) ? wsum[lane] : 0;
        int si = s;
        #pragma unroll
        for (int off = 1; off < 16; off <<= 1) {
            int u = __shfl_up(si, off, 64);
            if (lane >= off) si += u;
        }
        if (lane < 16) wsum[lane] = si - s;
    }
    __syncthreads();
    int excl = incl - v + wsum[w];
    if (i < n) start[i] = excl;
    if (threadIdx.x == 1023) bsum[blockIdx.x] = excl + v;
}

__global__ void k_scan2(int* __restrict__ bsum, int nb) {
    int lane = threadIdx.x;
    if (lane >= 64) return;
    int v = (lane < nb) ? bsum[lane] : 0;
    int incl = v;
    #pragma unroll
    for (int off = 1; off < 64; off <<= 1) {
        int u = __shfl_up(incl, off, 64);
        if (lane >= off) incl += u;
    }
    if (lane < nb) bsum[lane] = incl - v;
}

__global__ void k_scan3(int* __restrict__ start, const int* __restrict__ bsum, int n) {
    int i = blockIdx.x * blockDim.x + threadIdx.x;
    if (i < n) start[i] += bsum[i >> 10];
}

__global__ __launch_bounds__(256) void k_sortfill(const int* __restrict__ row,
                                                  const int* __restrict__ col,
                                                  const unsigned short* __restrict__ cntP,
                                                  const int* __restrict__ start,
                                                  int* __restrict__ er,
                                                  int E, int N, int slice) {
    __shared__ int cur[SBINS];
    int blk = blockIdx.x;
    int lo = blockIdx.y * SBINS;
    int span = min(SBINS, N - lo);
    for (int i = threadIdx.x; i < span; i += 256)
        cur[i] = start[lo + i] + (int)cntP[(size_t)blk * N + lo + i];
    __syncthreads();
    int e0 = blk * slice, e1 = min(e0 + slice, E);
    for (int e = e0 + threadIdx.x; e < e1; e += 256) {
        int c = col[e] - lo;
        int rv = row[e];
        if ((unsigned)c < (unsigned)span) {
            int pos = atomicAdd(&cur[c], 1);          // LDS fetch-add
            er[pos] = rv;
        }
    }
}

// ---------------- main pipeline ----------------

__global__ __launch_bounds__(256) void k_gather1(const int* __restrict__ er,
                                                 const int* __restrict__ start,
                                                 const int* __restrict__ cnt,
                                                 const float* __restrict__ dis,
                                                 const float* __restrict__ x,
                                                 float* __restrict__ Tx, int n) {
    int i = blockIdx.x * 4 + (threadIdx.x >> 6);
    if (i >= n) return;
    int lane = threadIdx.x & 63;
    int q = lane >> 4;
    int s4 = (lane & 15) * 4;
    int s = start[i], nd = cnt[i];
    float di = dis[i];
    float4 acc = make_float4(0.f, 0.f, 0.f, 0.f);
    int k = q;
    for (; k + 4 < nd; k += 8) {
        int r0 = er[s + k], r1 = er[s + k + 4];
        float w0 = -dis[r0] * di, w1 = -dis[r1] * di;
        float4 v0 = *reinterpret_cast<const float4*>(&x[(size_t)r0 * HDIM + s4]);
        float4 v1 = *reinterpret_cast<const float4*>(&x[(size_t)r1 * HDIM + s4]);
        acc.x = fmaf(w0, v0.x, acc.x); acc.y = fmaf(w0, v0.y, acc.y);
        acc.z = fmaf(w0, v0.z, acc.z); acc.w = fmaf(w0, v0.w, acc.w);
        acc.x = fmaf(w1, v1.x, acc.x); acc.y = fmaf(w1, v1.y, acc.y);
        acc.z = fmaf(w1, v1.z, acc.z); acc.w = fmaf(w1, v1.w, acc.w);
    }
    if (k < nd) {
        int r0 = er[s + k];
        float w0 = -dis[r0] * di;
        float4 v0 = *reinterpret_cast<const float4*>(&x[(size_t)r0 * HDIM + s4]);
        acc.x = fmaf(w0, v0.x, acc.x); acc.y = fmaf(w0, v0.y, acc.y);
        acc.z = fmaf(w0, v0.z, acc.z); acc.w = fmaf(w0, v0.w, acc.w);
    }
    #pragma unroll
    for (int off = 16; off <= 32; off <<= 1) {
        acc.x += __shfl_xor(acc.x, off, 64);
        acc.y += __shfl_xor(acc.y, off, 64);
        acc.z += __shfl_xor(acc.z, off, 64);
        acc.w += __shfl_xor(acc.w, off, 64);
    }
    if (q == 0) *reinterpret_cast<float4*>(&Tx[(size_t)i * HDIM + s4]) = acc;
}

// h = x@W1[0] + Tx1@W1[1] + b1, in-place over Tx1. Matrix-split: 512 threads,
// half 0 = x@W0 for col j, half 1 = t@W1 for col j -> each thread holds only
// 64 W floats (16 float4, statically indexed -> resident). Halves combine via
// an 8 KB LDS partial buffer. One 32-row tile per block, grid = ceil(n/32).
// Per-block col sum/sumsq written coalesced to pstat (reduced by k_statred).
__global__ __launch_bounds__(512) void k_gemm1(const float* __restrict__ x,
                                               float* __restrict__ TxH,
                                               const float* __restrict__ W1,
                                               const float* __restrict__ b1,
                                               float* __restrict__ pstat, int n) {
    __shared__ float xs[GR][HDIM];      // 8 KB
    __shared__ float ts[GR][HDIM];      // 8 KB
    __shared__ float pl[GR][HDIM];      // 8 KB partials / stats scratch
    int tid  = threadIdx.x;
    int j    = tid & 63;
    int half = (tid >> 6) & 1;
    int w2   = tid >> 7;                // 0..3 -> rows w2*8 .. w2*8+7
    int base = blockIdx.x * GR;

    const float* Wb = W1 + (half ? HDIM * HDIM : 0);
    float4 wr[16];
    #pragma unroll
    for (int k4 = 0; k4 < 16; ++k4) {
        wr[k4].x = Wb[(k4 * 4 + 0) * HDIM + j];
        wr[k4].y = Wb[(k4 * 4 + 1) * HDIM + j];
        wr[k4].z = Wb[(k4 * 4 + 2) * HDIM + j];
        wr[k4].w = Wb[(k4 * 4 + 3) * HDIM + j];
    }
    float bj = b1[j];

    // stage 32-row tile (clamped rows for the tail block)
    {
        int v = tid;                     // 512 = 32 rows x 16 float4
        int r = base + (v >> 4);
        int rc = min(r, n - 1);
        int c = (v & 15) * 4;
        ((float4*)xs)[v] = *(const float4*)&x[(size_t)rc * HDIM + c];
        ((float4*)ts)[v] = *(const float4*)&TxH[(size_t)rc * HDIM + c];
    }
    __syncthreads();

    const float(*src)[HDIM] = half ? ts : xs;
    float acc[8];
    #pragma unroll
    for (int m = 0; m < 8; ++m) {
        int lr = w2 * 8 + m;
        const float4* rp = (const float4*)src[lr];
        float a = 0.f;
        #pragma unroll
        for (int k4 = 0; k4 < 16; ++k4) {
            float4 v = rp[k4];
            a = fmaf(v.x, wr[k4].x, a);
            a = fmaf(v.y, wr[k4].y, a);
            a = fmaf(v.z, wr[k4].z, a);
            a = fmaf(v.w, wr[k4].w, a);
        }
        acc[m] = a;
    }

    if (half == 1) {
        #pragma unroll
        for (int m = 0; m < 8; ++m) pl[w2 * 8 + m][j] = acc[m];
    }
    __syncthreads();

    float sacc = 0.f, ssacc = 0.f;
    if (half == 0) {
        #pragma unroll
        for (int m = 0; m < 8; ++m) {
            int lr = w2 * 8 + m;
            int r = base + lr;
            if (r < n) {
                float tot = acc[m] + pl[lr][j] + bj;
                TxH[(size_t)r * HDIM + j] = tot;
                sacc += tot;
                ssacc = fmaf(tot, tot, ssacc);
            }
        }
    }
    __syncthreads();
    if (half == 0) {
        pl[w2][j]     = sacc;
        pl[4 + w2][j] = ssacc;
    }
    __syncthreads();
    if (half == 0 && w2 == 0) {
        float s  = pl[0][j] + pl[1][j] + pl[2][j] + pl[3][j];
        float ss = pl[4][j] + pl[5][j] + pl[6][j] + pl[7][j];
        pstat[(size_t)blockIdx.x * 128 + j]      = s;
        pstat[(size_t)blockIdx.x * 128 + 64 + j] = ss;
    }
}

// Reduce pstat over blocks: stats[idx] = sum_b pstat[b][idx], idx in [0,128)
__global__ __launch_bounds__(256) void k_statred(const float* __restrict__ pstat,
                                                 float* __restrict__ stats, int nb) {
    int idx = blockIdx.x;
    float s = 0.f;
    for (int b = threadIdx.x; b < nb; b += 256)
        s += pstat[(size_t)b * 128 + idx];
    __shared__ float red[256];
    red[threadIdx.x] = s;
    __syncthreads();
    for (int off = 128; off > 0; off >>= 1) {
        if (threadIdx.x < off) red[threadIdx.x] += red[threadIdx.x + off];
        __syncthreads();
    }
    if (threadIdx.x == 0) stats[idx] = red[0];
}

__global__ void k_prep(const float* __restrict__ stats,
                       const float* __restrict__ gamma, const float* __restrict__ beta,
                       const float* __restrict__ W2, const float* __restrict__ b2,
                       const float* __restrict__ linW, const float* __restrict__ linb,
                       float* __restrict__ scale, float* __restrict__ shift,
                       float* __restrict__ u0, float* __restrict__ u1,
                       float* __restrict__ c0, int n) {
    int k = threadIdx.x;
    if (k >= HDIM) return;
    float inv_n = 1.0f / (float)n;
    float mu  = stats[k] * inv_n;
    float var = stats[64 + k] * inv_n - mu * mu;
    float rs  = rsqrtf(var + 1e-5f);
    float sc  = rs * gamma[k];
    scale[k] = sc;
    shift[k] = beta[k] - mu * sc;
    float a0 = 0.f, a1 = 0.f;
    #pragma unroll 8
    for (int j = 0; j < HDIM; ++j) {
        float lw = linW[j];
        a0 = fmaf(W2[k * HDIM + j], lw, a0);
        a1 = fmaf(W2[HDIM * HDIM + k * HDIM + j], lw, a1);
    }
    u0[k] = a0;
    u1[k] = a1;
    if (k == 0) {
        float c = linb[0];
        for (int j = 0; j < HDIM; ++j) c = fmaf(b2[j], linW[j], c);
        c0[0] = c;
    }
}

__global__ __launch_bounds__(256) void k_node(const float* __restrict__ h,
                                              const float* __restrict__ scale,
                                              const float* __restrict__ shift,
                                              const float* __restrict__ u0,
                                              const float* __restrict__ u1,
                                              float* __restrict__ a, float* __restrict__ t,
                                              int n) {
    int i = blockIdx.x * 4 + (threadIdx.x >> 6);
    if (i >= n) return;
    int j = threadIdx.x & 63;
    float v = fmaf(h[(size_t)i * HDIM + j], scale[j], shift[j]);
    v = v >= 0.f ? v : 0.01f * v;
    float p0 = v * u0[j];
    float p1 = v * u1[j];
    #pragma unroll
    for (int off = 32; off > 0; off >>= 1) {
        p0 += __shfl_xor(p0, off, 64);
        p1 += __shfl_xor(p1, off, 64);
    }
    if (j == 0) { a[i] = p0; t[i] = p1; }
}

__global__ void k_gather2(const int* __restrict__ er, const int* __restrict__ start,
                          const int* __restrict__ cnt, const float* __restrict__ dis,
                          const float* __restrict__ t, const float* __restrict__ a,
                          float* __restrict__ s2, int n) {
    int i = blockIdx.x * blockDim.x + threadIdx.x;
    if (i >= n) return;
    int s = start[i], nd = cnt[i];
    float di = dis[i];
    float acc = a[i];
    int k = 0;
    for (; k + 1 < nd; k += 2) {
        int r0 = er[s + k], r1 = er[s + k + 1];
        float v0 = -dis[r0] * di * t[r0];
        float v1 = -dis[r1] * di * t[r1];
        acc += v0 + v1;
    }
    if (k < nd) {
        int r0 = er[s + k];
        acc = fmaf(-dis[r0] * di, t[r0], acc);
    }
    s2[i] = acc;
}

__global__ __launch_bounds__(256) void k_pool2(const float* __restrict__ s2,
                                               const int* __restrict__ batch,
                                               const float* __restrict__ c0,
                                               const float* __restrict__ linb,
                                               float* __restrict__ out, int n) {
    int g = blockIdx.x;
    int lo = lbound(batch, n, g);
    int hi = lbound(batch, n, g + 1);
    float s = 0.f;
    for (int i = lo + threadIdx.x; i < hi; i += 256) s += s2[i];
    __shared__ float red[256];
    red[threadIdx.x] = s;
    __syncthreads();
    for (int off = 128; off > 0; off >>= 1) {
        if (threadIdx.x < off) red[threadIdx.x] += red[threadIdx.x + off];
        __syncthreads();
    }
    if (threadIdx.x == 0) {
        int cntg = hi - lo;
        out[g] = cntg > 0 ? red[0] / (float)cntg + c0[0] : linb[0];
    }
}

// ---------------- launch ----------------

extern "C" void kernel_launch(void* const* d_in, const int* in_sizes, int n_in,
                              void* d_out, int out_size, void* d_ws, size_t ws_size,
                              hipStream_t stream) {
    const float* x     = (const float*)d_in[0];
    const int*   eidx  = (const int*)d_in[1];
    const int*   batch = (const int*)d_in[2];
    const float* W1    = (const float*)d_in[3];
    const float* b1    = (const float*)d_in[4];
    const float* W2    = (const float*)d_in[5];
    const float* b2    = (const float*)d_in[6];
    const float* gamma = (const float*)d_in[7];
    const float* beta  = (const float*)d_in[8];
    const float* linW  = (const float*)d_in[9];
    const float* linb  = (const float*)d_in[10];
    float* out = (float*)d_out;

    const int N = in_sizes[0] / HDIM;       // 50000
    const int E = in_sizes[1] / 2;          // 800000
    const int G = out_size;                 // 100
    const int NB = (N + 1023) / 1024;       // scan blocks (49 <= 64)
    const int slice = (E + BH - 1) / BH;    // 12500
    const int NGB = (N + GR - 1) / GR;      // gemm blocks (1563)

    const int* row = eidx;
    const int* col = eidx + E;

    // ---- workspace layout ----
    char* wsb = (char*)d_ws;
    float* TxH  = (float*)wsb;               wsb += (size_t)N * HDIM * 4;
    unsigned short* cntP = (unsigned short*)TxH;            // BH*N u16 (overlay)
    unsigned short* degP = cntP + (size_t)BH * N;           // BH*N u16 (overlay)
    int*   cnt   = (int*)wsb;                wsb += (size_t)N * 4;
    int*   start = (int*)wsb;                wsb += (size_t)N * 4;
    int*   bsum  = (int*)wsb;                wsb += (size_t)NB * 4 + 64;
    int*   er    = (int*)wsb;                wsb += (size_t)E * 4;
    float* dis   = (float*)wsb;              wsb += (size_t)N * 4;
    float* a     = (float*)wsb;              wsb += (size_t)N * 4;
    float* t     = (float*)wsb;              wsb += (size_t)N * 4;
    float* s2    = (float*)wsb;              wsb += (size_t)N * 4;
    float* pstat = (float*)wsb;              wsb += (size_t)NGB * 128 * 4;
    float* stats = (float*)wsb;              wsb += 128 * 4;
    float* scale = (float*)wsb;              wsb += HDIM * 4;
    float* shift = (float*)wsb;              wsb += HDIM * 4;
    float* u0    = (float*)wsb;              wsb += HDIM * 4;
    float* u1    = (float*)wsb;              wsb += HDIM * 4;
    float* c0    = (float*)wsb;              wsb += 64;

    k_histP<<<dim3(BH, 4), 256, 0, stream>>>(row, col, cntP, degP, E, N, slice);
    k_prefA<<<(N + 255) / 256, 256, 0, stream>>>(cntP, degP, cnt, dis, N);
    k_scan1<<<NB, 1024, 0, stream>>>(cnt, start, bsum, N);
    k_scan2<<<1, 64, 0, stream>>>(bsum, NB);
    k_scan3<<<(N + 255) / 256, 256, 0, stream>>>(start, bsum, N);
    k_sortfill<<<dim3(BH, 4), 256, 0, stream>>>(row, col, cntP, start, er, E, N, slice);
    k_gather1<<<(N + 3) / 4, 256, 0, stream>>>(er, start, cnt, dis, x, TxH, N);
    k_gemm1<<<NGB, 512, 0, stream>>>(x, TxH, W1, b1, pstat, N);
    k_statred<<<128, 256, 0, stream>>>(pstat, stats, NGB);
    k_prep<<<1, 64, 0, stream>>>(stats, gamma, beta, W2, b2, linW, linb,
                                 scale, shift, u0, u1, c0, N);
    k_node<<<(N + 3) / 4, 256, 0, stream>>>(TxH, scale, shift, u0, u1, a, t, N);
    k_gather2<<<(N + 255) / 256, 256, 0, stream>>>(er, start, cnt, dis, t, a, s2, N);
    k_pool2<<<G, 256, 0, stream>>>(s2, batch, c0, linb, out, N);
}